// Round 10
// baseline (1178.668 us; speedup 1.0000x reference)
//
#include <hip/hip_runtime.h>
#include <math.h>

#define NAGENT 10
#define OBS_D  64
#define HID    50
#define NSYM   10
#define NEGV   (-1e9f)

#define TPB 64               // one wave per block
#define BPW 6                // batch elements per block (60 active lanes)
#define AG  60

// ---- packed weight layout in d_ws (floats); rows contiguous per pass/chunk.
#define P_ENC0 0        // enc ch0: 65 rows x 28   (bias, obs k=0..63) j0..27
#define P_ENC1 1820     // enc ch1: 65 rows x 24   j28..49 (+2 pad)
#define P_F00  3380     // f0  ch0: 61 rows x 28   (bias, c x10, h0 x50)
#define P_F01  5088     // f0  ch1: 61 rows x 24
#define P_F1A  6552     // f1  cA : 111 rows x 20  (bias, c x10, h0 x50, h1 x50) j0..19
#define P_F1B  8772     // f1  cB : 111 rows x 16  j20..35
#define P_F1C  10548    // f1  cC : 111 rows x 16  j36..49 (+2 pad)
#define P_CM   12324    // comm   : 51 rows x 12   (bias, h x50) j0..9 (+2 pad)
#define P_HD   12936    // heads  : 50 rows x 4    [wpi0, wpi1, wv, 0]
#define TOT    13136

typedef float v2f __attribute__((ext_vector_type(2)));
struct W2 { v2f a, b; };
#define B2(F) __builtin_bit_cast(W2, F)
#define SB()  __builtin_amdgcn_sched_barrier(0)

static __device__ __forceinline__ v2f pk_fma(v2f a, v2f b, v2f c) {
  v2f d;
  asm("v_pk_fma_f32 %0, %1, %2, %3" : "=v"(d) : "v"(a), "v"(b), "v"(c));
  return d;
}

static __device__ __forceinline__ float fast_tanh(float x) {
  float xc = fminf(15.f, fmaxf(-15.f, x));
  float e  = __expf(2.f * xc);
  return __fdividef(e - 1.f, e + 1.f);
}

// one weight row: NF float4 loads (walking pointer) + 2*NF pk_fma against splat(x)
template<int NF>
static __device__ __forceinline__ void rowf(v2f* acc, const float4* p, float x) {
  float4 w[NF];
  #pragma unroll
  for (int i = 0; i < NF; i++) w[i] = p[i];
  v2f xx = {x, x};
  #pragma unroll
  for (int i = 0; i < NF; i++) {
    W2 h = B2(w[i]);
    acc[2*i]   = pk_fma(h.a, xx, acc[2*i]);
    acc[2*i+1] = pk_fma(h.b, xx, acc[2*i+1]);
  }
}
template<int NF>
static __device__ __forceinline__ void rowb(v2f* acc, const float4* p) {  // bias row
  float4 w[NF];
  #pragma unroll
  for (int i = 0; i < NF; i++) w[i] = p[i];
  #pragma unroll
  for (int i = 0; i < NF; i++) { W2 h = B2(w[i]); acc[2*i] = h.a; acc[2*i+1] = h.b; }
}

// ---------------- prep ----------------
__device__ __forceinline__ float encw(const float* W_enc, const float* b_enc, int r, int j) {
  return (r == 0) ? b_enc[j] : W_enc[(r-1)*HID + j];
}
__device__ __forceinline__ float f0w(const float* W_f, const float* b_f, int r, int j) {
  if (r == 0)  return b_f[j];
  if (r <= 10) return W_f[(50 + (r-1)) * HID + j];
  int k = r - 11; return W_f[k * HID + j] + W_f[(60 + k) * HID + j];
}
__device__ __forceinline__ float f1w(const float* W_f, const float* b_f, int r, int j) {
  if (r == 0)  return b_f[HID + j];
  if (r <= 10) return W_f[(110 + 50 + (r-1)) * HID + j];
  if (r <= 60) return W_f[(110 + 60 + (r-11)) * HID + j];   // skip (h0)
  return W_f[(110 + (r-61)) * HID + j];                     // h1
}

__global__ void prep_weights(const float* __restrict__ W_enc,
                             const float* __restrict__ W_f,
                             const float* __restrict__ W_comm,
                             const float* __restrict__ W_pi,
                             const float* __restrict__ W_v,
                             const float* __restrict__ b_enc,
                             const float* __restrict__ b_f,
                             const float* __restrict__ b_comm,
                             float* __restrict__ ws) {
  int i = blockIdx.x * blockDim.x + threadIdx.x;
  if (i >= TOT) return;
  float v = 0.f;
  if (i < P_ENC1)      { int r = i/28, j = i%28;                 v = encw(W_enc,b_enc,r,j); }
  else if (i < P_F00)  { int q=i-P_ENC1, r=q/24, j=28+q%24;      if (j<HID) v = encw(W_enc,b_enc,r,j); }
  else if (i < P_F01)  { int q=i-P_F00,  r=q/28, j=q%28;         v = f0w(W_f,b_f,r,j); }
  else if (i < P_F1A)  { int q=i-P_F01,  r=q/24, j=28+q%24;      if (j<HID) v = f0w(W_f,b_f,r,j); }
  else if (i < P_F1B)  { int q=i-P_F1A,  r=q/20, j=q%20;         v = f1w(W_f,b_f,r,j); }
  else if (i < P_F1C)  { int q=i-P_F1B,  r=q/16, j=20+q%16;      v = f1w(W_f,b_f,r,j); }
  else if (i < P_CM)   { int q=i-P_F1C,  r=q/16, j=36+q%16;      if (j<HID) v = f1w(W_f,b_f,r,j); }
  else if (i < P_HD)   { int q=i-P_CM,   r=q/12, c=q%12;         if (c<NSYM) v = (r==0)? b_comm[c] : W_comm[(r-1)*NSYM + c]; }
  else                 { int q=i-P_HD,   r=q/4,  c=q%4;          v = (c==0)?W_pi[2*r]:(c==1)?W_pi[2*r+1]:(c==2)?W_v[r]:0.f; }
  ws[i] = v;
}

__device__ __forceinline__ int comm_pick(const float cl[NSYM], float mk, float& clp) {
  float clm[NSYM];
  #pragma unroll
  for (int s = 0; s < NSYM; s++) clm[s] = (mk == 0.f) ? NEGV : cl[s];
  int w = 0; float best = clm[0];
  #pragma unroll
  for (int s = 1; s < NSYM; s++) { bool b = clm[s] > best; best = b ? clm[s] : best; w = b ? s : w; }
  float se = 0.f;
  #pragma unroll
  for (int s = 0; s < NSYM; s++) se += __expf(clm[s] - best);
  clp += (-__logf(se)) * mk;
  return w;
}

__global__ __launch_bounds__(TPB)
void policy_kernel(const float* __restrict__ obs,
                   const float* __restrict__ mask,
                   const float* __restrict__ b_pi,
                   const float* __restrict__ b_v,
                   const float* __restrict__ wsP,
                   float* __restrict__ out,
                   int B)
{
  const int t = threadIdx.x;
  const int beW  = blockIdx.x * BPW;
  const int bel  = t / NAGENT;
  const int aidx = t % NAGENT;
  const long long NA = (long long)B * NAGENT;
  const bool act = (t < AG) && (beW + bel < B);
  const long long g  = (long long)(beW + bel) * NAGENT + aidx;
  const long long gc = act ? g : 0;
  const int sh = bel * NAGENT;

  // divergence poison: LDS readback of 0 — compiler must treat as divergent,
  // so every weight pointer stays a per-lane VMEM base (never s_load).
  __shared__ int zsh[1];
  zsh[0] = 0;
  __syncthreads();
  const float* W = wsP + zsh[0];

  const float mk = mask[gc];
  float l0 = b_pi[0], l1 = b_pi[1], bv = b_v[0];

  // obs into registers (static indexing; dies after enc)
  float ox[OBS_D];
  {
    const float4* o4 = (const float4*)(obs + gc * OBS_D);
    #pragma unroll
    for (int q = 0; q < 16; q++) {
      float4 v = o4[q];
      ox[4*q] = v.x; ox[4*q+1] = v.y; ox[4*q+2] = v.z; ox[4*q+3] = v.w;
    }
  }

  float h0[HID], h1[HID];
  float clp = 0.f;
  float c_reg[NSYM];
  int w;

  // ================= enc ch0 (j0..27) =================
  {
    const float4* p = (const float4*)(W + P_ENC0);
    v2f acc[14];
    rowb<7>(acc, p); p += 7;
    #pragma unroll
    for (int k = 0; k < OBS_D; k++) { rowf<7>(acc, p, ox[k]); p += 7; if (k & 1) SB(); }
    #pragma unroll
    for (int i = 0; i < 14; i++) { h0[2*i] = fast_tanh(acc[i].x); h0[2*i+1] = fast_tanh(acc[i].y); }
  }
  // ================= enc ch1 (j28..49) =================
  {
    const float4* p = (const float4*)(W + P_ENC1);
    v2f acc[12];
    rowb<6>(acc, p); p += 6;
    #pragma unroll
    for (int k = 0; k < OBS_D; k++) { rowf<6>(acc, p, ox[k]); p += 6; if (k & 1) SB(); }
    #pragma unroll
    for (int i = 0; i < 11; i++) { h0[28+2*i] = fast_tanh(acc[i].x); h0[28+2*i+1] = fast_tanh(acc[i].y); }
  }

  // ================= comm step 0 (on h0) =================
  {
    const float4* p = (const float4*)(W + P_CM);
    v2f acc[6];
    rowb<3>(acc, p); p += 3;
    #pragma unroll
    for (int k = 0; k < HID; k++) { rowf<3>(acc, p, h0[k]); p += 3; if (k & 1) SB(); }
    float cl[NSYM];
    #pragma unroll
    for (int i = 0; i < 5; i++) { cl[2*i] = acc[i].x; cl[2*i+1] = acc[i].y; }
    w = comm_pick(cl, mk, clp);
  }
  #pragma unroll
  for (int s = 0; s < NSYM; s++) {
    unsigned long long b = __ballot(w == s);
    c_reg[s] = ((b >> sh) & 0x3FFULL) ? 1.f : 0.f;
  }

  // ================= f0 ch0 -> h1 j0..27 =================
  {
    const float4* p = (const float4*)(W + P_F00);
    v2f acc[14];
    rowb<7>(acc, p); p += 7;
    #pragma unroll
    for (int s = 0; s < NSYM; s++) { rowf<7>(acc, p, c_reg[s]); p += 7; if (s & 1) SB(); }
    #pragma unroll
    for (int k = 0; k < HID; k++) { rowf<7>(acc, p, h0[k]); p += 7; if (k & 1) SB(); }
    #pragma unroll
    for (int i = 0; i < 14; i++) { h1[2*i] = fast_tanh(acc[i].x); h1[2*i+1] = fast_tanh(acc[i].y); }
  }
  // ================= f0 ch1 -> h1 j28..49 =================
  {
    const float4* p = (const float4*)(W + P_F01);
    v2f acc[12];
    rowb<6>(acc, p); p += 6;
    #pragma unroll
    for (int s = 0; s < NSYM; s++) { rowf<6>(acc, p, c_reg[s]); p += 6; if (s & 1) SB(); }
    #pragma unroll
    for (int k = 0; k < HID; k++) { rowf<6>(acc, p, h0[k]); p += 6; if (k & 1) SB(); }
    #pragma unroll
    for (int i = 0; i < 11; i++) { h1[28+2*i] = fast_tanh(acc[i].x); h1[28+2*i+1] = fast_tanh(acc[i].y); }
  }

  // ================= comm step 1 (on h1) =================
  {
    const float4* p = (const float4*)(W + P_CM);
    v2f acc[6];
    rowb<3>(acc, p); p += 3;
    #pragma unroll
    for (int k = 0; k < HID; k++) { rowf<3>(acc, p, h1[k]); p += 3; if (k & 1) SB(); }
    float cl[NSYM];
    #pragma unroll
    for (int i = 0; i < 5; i++) { cl[2*i] = acc[i].x; cl[2*i+1] = acc[i].y; }
    w = comm_pick(cl, mk, clp);
  }
  #pragma unroll
  for (int s = 0; s < NSYM; s++) {
    unsigned long long b = __ballot(w == s);
    c_reg[s] = ((b >> sh) & 0x3FFULL) ? 1.f : 0.f;   // step-1 c = output c
  }

  // ================= f1 in 3 j-chunks + fused heads =================
  const float4* ph = (const float4*)(W + P_HD);
  // ---- cA: j0..19
  {
    const float4* p = (const float4*)(W + P_F1A);
    v2f acc[10];
    rowb<5>(acc, p); p += 5;
    #pragma unroll
    for (int s = 0; s < NSYM; s++) { rowf<5>(acc, p, c_reg[s]); p += 5; if (s & 1) SB(); }
    #pragma unroll
    for (int k = 0; k < HID; k++) { rowf<5>(acc, p, h0[k]); p += 5; if (k & 1) SB(); }
    #pragma unroll
    for (int k = 0; k < HID; k++) { rowf<5>(acc, p, h1[k]); p += 5; if (k & 1) SB(); }
    #pragma unroll
    for (int j = 0; j < 20; j++) {
      float hh = fast_tanh((j & 1) ? acc[j/2].y : acc[j/2].x);
      float4 hw = ph[j];
      l0 = fmaf(hh, hw.x, l0); l1 = fmaf(hh, hw.y, l1); bv = fmaf(hh, hw.z, bv);
      if (j & 1) SB();
    }
  }
  // ---- cB: j20..35
  {
    const float4* p = (const float4*)(W + P_F1B);
    v2f acc[8];
    rowb<4>(acc, p); p += 4;
    #pragma unroll
    for (int s = 0; s < NSYM; s++) { rowf<4>(acc, p, c_reg[s]); p += 4; if (s & 1) SB(); }
    #pragma unroll
    for (int k = 0; k < HID; k++) { rowf<4>(acc, p, h0[k]); p += 4; if (k & 1) SB(); }
    #pragma unroll
    for (int k = 0; k < HID; k++) { rowf<4>(acc, p, h1[k]); p += 4; if (k & 1) SB(); }
    #pragma unroll
    for (int j = 0; j < 16; j++) {
      float hh = fast_tanh((j & 1) ? acc[j/2].y : acc[j/2].x);
      float4 hw = ph[20 + j];
      l0 = fmaf(hh, hw.x, l0); l1 = fmaf(hh, hw.y, l1); bv = fmaf(hh, hw.z, bv);
      if (j & 1) SB();
    }
  }
  // ---- cC: j36..49
  {
    const float4* p = (const float4*)(W + P_F1C);
    v2f acc[8];
    rowb<4>(acc, p); p += 4;
    #pragma unroll
    for (int s = 0; s < NSYM; s++) { rowf<4>(acc, p, c_reg[s]); p += 4; if (s & 1) SB(); }
    #pragma unroll
    for (int k = 0; k < HID; k++) { rowf<4>(acc, p, h0[k]); p += 4; if (k & 1) SB(); }
    #pragma unroll
    for (int k = 0; k < HID; k++) { rowf<4>(acc, p, h1[k]); p += 4; if (k & 1) SB(); }
    #pragma unroll
    for (int j = 0; j < 14; j++) {
      float hh = fast_tanh((j & 1) ? acc[j/2].y : acc[j/2].x);
      float4 hw = ph[36 + j];
      l0 = fmaf(hh, hw.x, l0); l1 = fmaf(hh, hw.y, l1); bv = fmaf(hh, hw.z, bv);
      if (j & 1) SB();
    }
  }

  // ================= outputs =================
  if (act) {
    float2* o2 = (float2*)out;
    o2[g] = make_float2((mk == 0.f) ? NEGV : l0, (mk == 0.f) ? NEGV : l1);
    out[NA * 2 + g] = bv * mk;
    out[NA * 3 + g] = clp;
    float2* c2 = (float2*)(out + NA * 4);
    const long long cb = g * (NSYM / 2);
    #pragma unroll
    for (int s = 0; s < NSYM / 2; s++)
      c2[cb + s] = make_float2(c_reg[2 * s], c_reg[2 * s + 1]);
  }
}

extern "C" void kernel_launch(void* const* d_in, const int* in_sizes, int n_in,
                              void* d_out, int out_size, void* d_ws, size_t ws_size,
                              hipStream_t stream) {
  const float* obs    = (const float*)d_in[0];
  const float* mask   = (const float*)d_in[1];
  const float* W_enc  = (const float*)d_in[2];
  const float* b_enc  = (const float*)d_in[3];
  const float* W_f    = (const float*)d_in[4];
  const float* b_f    = (const float*)d_in[5];
  const float* W_comm = (const float*)d_in[6];
  const float* b_comm = (const float*)d_in[7];
  const float* W_pi   = (const float*)d_in[8];
  const float* b_pi   = (const float*)d_in[9];
  const float* W_v    = (const float*)d_in[10];
  const float* b_v    = (const float*)d_in[11];
  float* out = (float*)d_out;
  float* ws  = (float*)d_ws;

  const int B = in_sizes[0] / (NAGENT * OBS_D);

  hipLaunchKernelGGL(prep_weights, dim3((TOT + 255) / 256), dim3(256), 0, stream,
                     W_enc, W_f, W_comm, W_pi, W_v, b_enc, b_f, b_comm, ws);

  const int grid = (B + BPW - 1) / BPW;
  hipLaunchKernelGGL(policy_kernel, dim3(grid), dim3(TPB), 0, stream,
                     obs, mask, b_pi, b_v, ws, out, B);
}